// Round 8
// baseline (39.432 us; speedup 1.0000x reference)
//
#include <hip/hip_runtime.h>
#include <hip/hip_bf16.h>
#include <math.h>

#define NSEQ 512
#define EMB 256

typedef __attribute__((ext_vector_type(8))) short bf16x8;
typedef __attribute__((ext_vector_type(4))) float f32x4;

// order-preserving float<->uint encoding for atomic max
__device__ __forceinline__ unsigned fenc(float f) {
    unsigned u = __float_as_uint(f);
    return (u & 0x80000000u) ? ~u : (u | 0x80000000u);
}
__device__ __forceinline__ float fdec(unsigned e) {
    unsigned u = (e & 0x80000000u) ? (e ^ 0x80000000u) : ~e;
    return __uint_as_float(u);
}

__device__ __forceinline__ unsigned short f2bf(float f) {
    unsigned u = __float_as_uint(f);
    unsigned r = (u + 0x7FFFu + ((u >> 16) & 1u)) >> 16;
    return (unsigned short)r;
}
__device__ __forceinline__ float bf2f(unsigned short s) {
    return __uint_as_float(((unsigned)s) << 16);
}
__device__ __forceinline__ ushort4 cvt4(float4 v) {
    ushort4 o;
    o.x = f2bf(v.x); o.y = f2bf(v.y); o.z = f2bf(v.z); o.w = f2bf(v.w);
    return o;
}

// K1: projections via bf16 MFMA, fp32 sources converted during staging.
//   blockIdx.y in 0..15: seg = y>>2 (0:Q' 1:K' 2:V 3:P), wbase = (y&3)*64
//     seg0: Qb[1024][256] = bf16(X(Wq-Wr)^T + bq)
//     seg1: Kb[1024][256] = bf16(X(Wk+Wr)^T)        (K-side bias cancels in softmax)
//     seg2: Vtb[16][32][512] = bf16(XWv^T + bv) transposed per (b,h)
//     seg3: P = XWr^T -> per-(batch,chan) max -> maxEnc (atomics)
//   blockIdx.y == 16: convert Wo fp32 -> Wob bf16 (piggyback, no extra dispatch)
// grid (16, 17) x 256 (4 waves). 64x64 tile, full K=256 in LDS.
__global__ __launch_bounds__(256) void k_gemm_mfma(
    const float* __restrict__ X,
    const float* __restrict__ Wq, const float* __restrict__ Wk,
    const float* __restrict__ Wv, const float* __restrict__ Wr,
    const float* __restrict__ Wo,
    const float* __restrict__ bq, const float* __restrict__ bv,
    unsigned short* __restrict__ Qb, unsigned short* __restrict__ Kb,
    unsigned short* __restrict__ Vtb, unsigned short* __restrict__ Wob,
    unsigned* __restrict__ maxEnc)
{
    const int t = threadIdx.x;

    if (blockIdx.y == 16) {   // Wo fp32 -> bf16, 16 blocks x 4 float4/thread
        const float4* Wg = (const float4*)Wo;
        #pragma unroll
        for (int i = 0; i < 4; ++i) {
            int idx4 = blockIdx.x * 1024 + i * 256 + t;   // 0..16383
            ((ushort4*)Wob)[idx4] = cvt4(Wg[idx4]);
        }
        return;
    }

    __shared__ __align__(16) unsigned short Xs[64 * 264];  // stride 264 bf16 = 528B
    __shared__ __align__(16) unsigned short Ws[64 * 264];
    __shared__ float red[4][64];

    const int w = t >> 6, l = t & 63;
    const int ln = l & 15, kg = l >> 4;
    const int m0 = blockIdx.x * 64;
    const int nW = blockIdx.y * 64;           // W row base
    const int seg = blockIdx.y >> 2;          // 0:Q' 1:K' 2:V 3:P
    const int wbase = (blockIdx.y & 3) * 64;

    const float4* X4  = (const float4*)X;     // [1024][64] float4
    const float4* Wq4 = (const float4*)Wq;
    const float4* Wk4 = (const float4*)Wk;
    const float4* Wv4 = (const float4*)Wv;
    const float4* Wr4 = (const float4*)Wr;

    // stage + convert: 64 rows x 256 k each for X and W
    #pragma unroll
    for (int i = 0; i < 16; ++i) {
        int idx = i * 256 + t;                // float4 index 0..4095
        int row = idx >> 6, c4 = idx & 63;
        float4 xv = X4[(size_t)(m0 + row) * 64 + c4];
        *(ushort4*)(Xs + row * 264 + c4 * 4) = cvt4(xv);

        size_t off = (size_t)(wbase + row) * 64 + c4;
        float4 wv;
        if (seg == 0) {
            float4 a = Wq4[off], r = Wr4[off];
            wv = make_float4(a.x - r.x, a.y - r.y, a.z - r.z, a.w - r.w);
        } else if (seg == 1) {
            float4 a = Wk4[off], r = Wr4[off];
            wv = make_float4(a.x + r.x, a.y + r.y, a.z + r.z, a.w + r.w);
        } else if (seg == 2) {
            wv = Wv4[off];
        } else {
            wv = Wr4[off];
        }
        *(ushort4*)(Ws + row * 264 + c4 * 4) = cvt4(wv);
    }
    __syncthreads();

    f32x4 acc[4] = {{0.f,0.f,0.f,0.f},{0.f,0.f,0.f,0.f},
                    {0.f,0.f,0.f,0.f},{0.f,0.f,0.f,0.f}};
    const int arow = (w << 4) + ln;
    #pragma unroll
    for (int ks = 0; ks < 8; ++ks) {
        bf16x8 a = *(const bf16x8*)(Xs + arow * 264 + ks * 32 + kg * 8);
        #pragma unroll
        for (int nf = 0; nf < 4; ++nf) {
            bf16x8 b = *(const bf16x8*)(Ws + (nf * 16 + ln) * 264 + ks * 32 + kg * 8);
            acc[nf] = __builtin_amdgcn_mfma_f32_16x16x32_bf16(a, b, acc[nf], 0, 0, 0);
        }
    }

    if (seg == 0) {
        #pragma unroll
        for (int nf = 0; nf < 4; ++nf) {
            int c = (nW & 255) + nf * 16 + ln;
            float bb = bq[c];
            #pragma unroll
            for (int r = 0; r < 4; ++r) {
                int row = m0 + w * 16 + kg * 4 + r;
                Qb[(size_t)row * 256 + c] = f2bf(acc[nf][r] + bb);
            }
        }
    } else if (seg == 1) {
        #pragma unroll
        for (int nf = 0; nf < 4; ++nf) {
            int c = (nW & 255) + nf * 16 + ln;
            #pragma unroll
            for (int r = 0; r < 4; ++r) {
                int row = m0 + w * 16 + kg * 4 + r;
                Kb[(size_t)row * 256 + c] = f2bf(acc[nf][r]);
            }
        }
    } else if (seg == 2) {
        #pragma unroll
        for (int nf = 0; nf < 4; ++nf) {
            int c = (nW & 255) + nf * 16 + ln;   // global channel 0..255
            int h = c >> 5, d = c & 31;
            float bb = bv[c];
            #pragma unroll
            for (int r = 0; r < 4; ++r) {
                int row = m0 + w * 16 + kg * 4 + r;
                int b = row >> 9, ml = row & 511;
                Vtb[((size_t)(b * 8 + h) * 32 + d) * 512 + ml] = f2bf(acc[nf][r] + bb);
            }
        }
    } else {
        #pragma unroll
        for (int nf = 0; nf < 4; ++nf) {
            float mx = fmaxf(fmaxf(acc[nf][0], acc[nf][1]),
                             fmaxf(acc[nf][2], acc[nf][3]));
            mx = fmaxf(mx, __shfl_xor(mx, 16));
            mx = fmaxf(mx, __shfl_xor(mx, 32));
            if (l < 16) red[w][nf * 16 + ln] = mx;
        }
        __syncthreads();
        if (t < 64) {
            float m = fmaxf(fmaxf(red[0][t], red[1][t]),
                            fmaxf(red[2][t], red[3][t]));
            atomicMax(&maxEnc[(m0 >> 9) * 256 + (nW & 255) + t], fenc(m));
        }
    }
}

// K2: MFMA flash attention (unchanged from round 7; passed at absmax 0.0156).
__global__ __launch_bounds__(256) void k_attn_mfma(
    const unsigned short* __restrict__ Qb,   // [1024][256] bf16
    const unsigned short* __restrict__ Kb,   // [1024][256] bf16
    const unsigned short* __restrict__ Vtb,  // [16][32][512] bf16
    const unsigned* __restrict__ maxEnc,
    const float* __restrict__ br,
    unsigned short* __restrict__ attnb)      // [1024][256] bf16
{
    __shared__ __align__(16) unsigned short Plds[4][16][136];
    __shared__ float Olds[4][16][33];
    __shared__ float mlds[4][16], llds[4][16];
    __shared__ float scl[4][16], Li[16];

    const int t = threadIdx.x;
    const int w = t >> 6, l = t & 63;
    const int ln = l & 15, kg = l >> 4;
    const int q0 = blockIdx.x * 16;
    const int h = blockIdx.y, b = blockIdx.z;
    const int e0 = h * 32;
    const int bh = b * 8 + h;
    const float scale = 0.17677669529663687f;  // 1/sqrt(32)

    // a-frag: Qr = (Qb + maxP + br) * scale, re-rounded to bf16
    bf16x8 af;
    {
        size_t qrow = (size_t)(b * NSEQ + q0 + ln) * 256 + e0 + kg * 8;
        bf16x8 qa = *(const bf16x8*)(Qb + qrow);
        #pragma unroll
        for (int j = 0; j < 8; ++j) {
            int d = kg * 8 + j;
            float qv = bf2f((unsigned short)qa[j]);
            float ad = fdec(maxEnc[b * 256 + e0 + d]) + br[e0 + d];
            af[j] = (short)f2bf((qv + ad) * scale);
        }
    }

    // QK^T: 8 key-frags of 16 (this wave's 128 keys)
    const int key0 = w * 128;
    f32x4 sc[8];
    #pragma unroll
    for (int kf = 0; kf < 8; ++kf) {
        size_t krow = (size_t)(b * NSEQ + key0 + kf * 16 + ln) * 256 + e0 + kg * 8;
        bf16x8 bfr = *(const bf16x8*)(Kb + krow);
        f32x4 z = {0.f, 0.f, 0.f, 0.f};
        sc[kf] = __builtin_amdgcn_mfma_f32_16x16x32_bf16(af, bfr, z, 0, 0, 0);
    }

    // single-pass softmax over this wave's 128 keys; lane owns q = kg*4+r
    float m_[4], l_[4];
    #pragma unroll
    for (int r = 0; r < 4; ++r) {
        float mx = sc[0][r];
        #pragma unroll
        for (int kf = 1; kf < 8; ++kf) mx = fmaxf(mx, sc[kf][r]);
        #pragma unroll
        for (int off = 1; off < 16; off <<= 1) mx = fmaxf(mx, __shfl_xor(mx, off));
        m_[r] = mx;
        float s = 0.f;
        #pragma unroll
        for (int kf = 0; kf < 8; ++kf) {
            float p = __expf(sc[kf][r] - mx);
            sc[kf][r] = p;
            s += p;
        }
        #pragma unroll
        for (int off = 1; off < 16; off <<= 1) s += __shfl_xor(s, off);
        l_[r] = s;
    }

    // P -> LDS (bf16), wave-private
    #pragma unroll
    for (int kf = 0; kf < 8; ++kf)
        #pragma unroll
        for (int r = 0; r < 4; ++r)
            Plds[w][kg * 4 + r][kf * 16 + ln] = f2bf(sc[kf][r]);

    // PV: O[16 q][32 d], a = P frags from LDS, b = Vt frags from global
    f32x4 o[2] = {{0.f,0.f,0.f,0.f},{0.f,0.f,0.f,0.f}};
    #pragma unroll
    for (int ks = 0; ks < 4; ++ks) {
        bf16x8 pf = *(const bf16x8*)&Plds[w][ln][ks * 32 + kg * 8];
        #pragma unroll
        for (int df = 0; df < 2; ++df) {
            size_t vrow = ((size_t)bh * 32 + df * 16 + ln) * 512 + key0 + ks * 32 + kg * 8;
            bf16x8 vf = *(const bf16x8*)(Vtb + vrow);
            o[df] = __builtin_amdgcn_mfma_f32_16x16x32_bf16(pf, vf, o[df], 0, 0, 0);
        }
    }

    // write partials
    if (ln == 0) {
        #pragma unroll
        for (int r = 0; r < 4; ++r) {
            mlds[w][kg * 4 + r] = m_[r];
            llds[w][kg * 4 + r] = l_[r];
        }
    }
    #pragma unroll
    for (int df = 0; df < 2; ++df)
        #pragma unroll
        for (int r = 0; r < 4; ++r)
            Olds[w][kg * 4 + r][df * 16 + ln] = o[df][r];
    __syncthreads();

    // combine scales per q (threads 0..15)
    if (t < 16) {
        float M = fmaxf(fmaxf(mlds[0][t], mlds[1][t]),
                        fmaxf(mlds[2][t], mlds[3][t]));
        float L = 0.f;
        #pragma unroll
        for (int wv = 0; wv < 4; ++wv) {
            float s = __expf(mlds[wv][t] - M);
            scl[wv][t] = s;
            L += s * llds[wv][t];
        }
        Li[t] = 1.f / L;
    }
    __syncthreads();

    // combine elements: 512 outputs, 2 per thread
    #pragma unroll
    for (int i = 0; i < 2; ++i) {
        int idx = t + 256 * i;
        int q = idx >> 5, d = idx & 31;
        float acc = 0.f;
        #pragma unroll
        for (int wv = 0; wv < 4; ++wv)
            acc += scl[wv][q] * Olds[wv][q][d];
        attnb[(size_t)(b * NSEQ + q0 + q) * 256 + e0 + d] = f2bf(acc * Li[q]);
    }
}

// K3: fused out-projection + residual + LN1 + LN2. grid 64 x 256 (4 waves).
// Block = 16 rows x all 256 cols, K=256. A staged in LDS; B (Wob) direct from
// global bf16 (L2-hot). Epilogue: y = x + bo + gemm; two LayerNorms in-block.
__global__ __launch_bounds__(256) void k_oln(
    const unsigned short* __restrict__ Ab,   // attnb [1024][256] bf16
    const unsigned short* __restrict__ Wob,  // [256][256] bf16
    const float* __restrict__ x, const float* __restrict__ bo,
    const float* __restrict__ g1, const float* __restrict__ b1,
    const float* __restrict__ g2, const float* __restrict__ b2,
    float* __restrict__ out)
{
    __shared__ __align__(16) unsigned short As_[16 * 264];
    __shared__ float ylds[16][257];

    const int t = threadIdx.x;
    const int w = t >> 6, l = t & 63;
    const int ln = l & 15, kg = l >> 4;
    const int m0 = blockIdx.x * 16;

    // stage A: 16 rows x 256 k
    const uint4* Ag = (const uint4*)Ab;       // [1024][32]
    #pragma unroll
    for (int i = 0; i < 2; ++i) {
        int idx = i * 256 + t;                // 0..511
        int row = idx >> 5, c8 = idx & 31;
        *(uint4*)(As_ + row * 264 + c8 * 8) = Ag[(size_t)(m0 + row) * 32 + c8];
    }
    __syncthreads();

    // GEMM: wave w owns cols w*64 .. w*64+63
    f32x4 acc[4] = {{0.f,0.f,0.f,0.f},{0.f,0.f,0.f,0.f},
                    {0.f,0.f,0.f,0.f},{0.f,0.f,0.f,0.f}};
    #pragma unroll
    for (int ks = 0; ks < 8; ++ks) {
        bf16x8 a = *(const bf16x8*)(As_ + ln * 264 + ks * 32 + kg * 8);
        #pragma unroll
        for (int nf = 0; nf < 4; ++nf) {
            int n = w * 64 + nf * 16 + ln;
            bf16x8 b = *(const bf16x8*)(Wob + (size_t)n * 256 + ks * 32 + kg * 8);
            acc[nf] = __builtin_amdgcn_mfma_f32_16x16x32_bf16(a, b, acc[nf], 0, 0, 0);
        }
    }

    // scatter to LDS: row = kg*4+r, col = w*64+nf*16+ln
    #pragma unroll
    for (int nf = 0; nf < 4; ++nf)
        #pragma unroll
        for (int r = 0; r < 4; ++r)
            ylds[kg * 4 + r][w * 64 + nf * 16 + ln] = acc[nf][r];
    __syncthreads();

    // LN: thread t handles row t>>4, channels (t&15)+16j
    const int row = t >> 4, lc = t & 15;
    const size_t gro = (size_t)(m0 + row) * 256;

    float y[16];
    float s = 0.f, s2 = 0.f;
    #pragma unroll
    for (int j = 0; j < 16; ++j) {
        int c = lc + 16 * j;
        float v = x[gro + c] + bo[c] + ylds[row][c];
        y[j] = v;
        s += v; s2 += v * v;
    }
    #pragma unroll
    for (int off = 1; off < 16; off <<= 1) {
        s  += __shfl_xor(s, off);
        s2 += __shfl_xor(s2, off);
    }
    float mu = s * (1.f / 256.f);
    float var = s2 * (1.f / 256.f) - mu * mu;
    float rs = rsqrtf(var + 1e-5f);

    float t1[16];
    s = 0.f; s2 = 0.f;
    #pragma unroll
    for (int j = 0; j < 16; ++j) {
        int c = lc + 16 * j;
        float v = (y[j] - mu) * rs * g1[c] + b1[c];
        t1[j] = v;
        s += v; s2 += v * v;
    }
    #pragma unroll
    for (int off = 1; off < 16; off <<= 1) {
        s  += __shfl_xor(s, off);
        s2 += __shfl_xor(s2, off);
    }
    mu = s * (1.f / 256.f);
    var = s2 * (1.f / 256.f) - mu * mu;
    rs = rsqrtf(var + 1e-5f);

    #pragma unroll
    for (int j = 0; j < 16; ++j) {
        int c = lc + 16 * j;
        out[gro + c] = (t1[j] - mu) * rs * g2[c] + b2[c];
    }
}

extern "C" void kernel_launch(void* const* d_in, const int* in_sizes, int n_in,
                              void* d_out, int out_size, void* d_ws, size_t ws_size,
                              hipStream_t stream)
{
    const float* x  = (const float*)d_in[0];
    const float* Wq = (const float*)d_in[1];
    const float* bq = (const float*)d_in[2];
    const float* Wk = (const float*)d_in[3];
    const float* bk = (const float*)d_in[4];   // cancels in softmax (unused)
    const float* Wv = (const float*)d_in[5];
    const float* bv = (const float*)d_in[6];
    const float* Wr = (const float*)d_in[7];
    const float* br = (const float*)d_in[8];
    const float* Wo = (const float*)d_in[9];
    const float* bo = (const float*)d_in[10];
    const float* g1 = (const float*)d_in[11];
    const float* b1 = (const float*)d_in[12];
    const float* g2 = (const float*)d_in[13];
    const float* b2 = (const float*)d_in[14];
    float* out = (float*)d_out;
    (void)bk;

    unsigned short* u = (unsigned short*)d_ws;
    unsigned short* Qb    = u;               // 1024*256
    unsigned short* Kb    = u + 262144;      // 1024*256
    unsigned short* Vtb   = u + 524288;      // 16*32*512
    unsigned short* attnb = u + 786432;      // 1024*256
    unsigned short* Wob   = u + 1048576;     // 256*256
    unsigned* maxEnc = (unsigned*)(u + 1114112);  // 512 (byte off 2228224, aligned)

    hipMemsetAsync(maxEnc, 0x00, 512 * sizeof(unsigned), stream);
    k_gemm_mfma<<<dim3(16, 17), 256, 0, stream>>>(x, Wq, Wk, Wv, Wr, Wo, bq, bv,
                                                  Qb, Kb, Vtb, Wob, maxEnc);
    k_attn_mfma<<<dim3(32, 8, 2), 256, 0, stream>>>(Qb, Kb, Vtb, maxEnc, br, attnb);
    k_oln<<<64, 256, 0, stream>>>(attnb, Wob, x, bo, g1, b1, g2, b2, out);
}

// Round 9
// 28.343 us; speedup vs baseline: 1.3913x; 1.3913x over previous
//
#include <hip/hip_runtime.h>
#include <hip/hip_bf16.h>
#include <math.h>

#define NSEQ 512
#define EMB 256

typedef __attribute__((ext_vector_type(8))) short bf16x8;
typedef __attribute__((ext_vector_type(4))) float f32x4;

__device__ __forceinline__ unsigned short f2bf(float f) {
    unsigned u = __float_as_uint(f);
    unsigned r = (u + 0x7FFFu + ((u >> 16) & 1u)) >> 16;
    return (unsigned short)r;
}
__device__ __forceinline__ float bf2f(unsigned short s) {
    return __uint_as_float(((unsigned)s) << 16);
}
__device__ __forceinline__ ushort4 cvt4(float4 v) {
    ushort4 o;
    o.x = f2bf(v.x); o.y = f2bf(v.y); o.z = f2bf(v.z); o.w = f2bf(v.w);
    return o;
}

// K1: projections via bf16 MFMA, fp32 sources converted during LDS staging.
//   blockIdx.y 0..15: seg = y>>2 (0:Q' 1:K' 2:V 3:P), wbase = (y&3)*64
//     seg0: Qb[1024][256] = bf16(X(Wq-Wr)^T + bq)
//     seg1: Kb[1024][256] = bf16(X(Wk+Wr)^T)      (K-side bias cancels in softmax)
//     seg2: Vtb[16][32][512] = bf16(XWv^T + bv) transposed per (b,h)
//     seg3: P = XWr^T -> per-block 64-row max -> maxPart[b][mblk][c] (no atomics)
//   blockIdx.y == 16: convert Wo fp32 -> Wob bf16 (piggyback)
// grid (16, 17) x 256 (4 waves). 64x64 tile, full K=256 in LDS.
__global__ __launch_bounds__(256) void k_gemm_mfma(
    const float* __restrict__ X,
    const float* __restrict__ Wq, const float* __restrict__ Wk,
    const float* __restrict__ Wv, const float* __restrict__ Wr,
    const float* __restrict__ Wo,
    const float* __restrict__ bq, const float* __restrict__ bv,
    unsigned short* __restrict__ Qb, unsigned short* __restrict__ Kb,
    unsigned short* __restrict__ Vtb, unsigned short* __restrict__ Wob,
    float* __restrict__ maxPart)   // [2][8][256]
{
    const int t = threadIdx.x;

    if (blockIdx.y == 16) {   // Wo fp32 -> bf16
        const float4* Wg = (const float4*)Wo;
        #pragma unroll
        for (int i = 0; i < 4; ++i) {
            int idx4 = blockIdx.x * 1024 + i * 256 + t;   // 0..16383
            ((ushort4*)Wob)[idx4] = cvt4(Wg[idx4]);
        }
        return;
    }

    __shared__ __align__(16) unsigned short Xs[64 * 264];  // stride 264 bf16 = 528B
    __shared__ __align__(16) unsigned short Ws[64 * 264];
    __shared__ float red[4][64];

    const int w = t >> 6, l = t & 63;
    const int ln = l & 15, kg = l >> 4;
    const int m0 = blockIdx.x * 64;
    const int nW = blockIdx.y * 64;
    const int seg = blockIdx.y >> 2;
    const int wbase = (blockIdx.y & 3) * 64;

    const float4* X4  = (const float4*)X;     // [1024][64] float4
    const float4* Wq4 = (const float4*)Wq;
    const float4* Wk4 = (const float4*)Wk;
    const float4* Wv4 = (const float4*)Wv;
    const float4* Wr4 = (const float4*)Wr;

    #pragma unroll
    for (int i = 0; i < 16; ++i) {
        int idx = i * 256 + t;                // float4 index 0..4095
        int row = idx >> 6, c4 = idx & 63;
        float4 xv = X4[(size_t)(m0 + row) * 64 + c4];
        *(ushort4*)(Xs + row * 264 + c4 * 4) = cvt4(xv);

        size_t off = (size_t)(wbase + row) * 64 + c4;
        float4 wv;
        if (seg == 0) {
            float4 a = Wq4[off], r = Wr4[off];
            wv = make_float4(a.x - r.x, a.y - r.y, a.z - r.z, a.w - r.w);
        } else if (seg == 1) {
            float4 a = Wk4[off], r = Wr4[off];
            wv = make_float4(a.x + r.x, a.y + r.y, a.z + r.z, a.w + r.w);
        } else if (seg == 2) {
            wv = Wv4[off];
        } else {
            wv = Wr4[off];
        }
        *(ushort4*)(Ws + row * 264 + c4 * 4) = cvt4(wv);
    }
    __syncthreads();

    f32x4 acc[4] = {{0.f,0.f,0.f,0.f},{0.f,0.f,0.f,0.f},
                    {0.f,0.f,0.f,0.f},{0.f,0.f,0.f,0.f}};
    const int arow = (w << 4) + ln;
    #pragma unroll
    for (int ks = 0; ks < 8; ++ks) {
        bf16x8 a = *(const bf16x8*)(Xs + arow * 264 + ks * 32 + kg * 8);
        #pragma unroll
        for (int nf = 0; nf < 4; ++nf) {
            bf16x8 b = *(const bf16x8*)(Ws + (nf * 16 + ln) * 264 + ks * 32 + kg * 8);
            acc[nf] = __builtin_amdgcn_mfma_f32_16x16x32_bf16(a, b, acc[nf], 0, 0, 0);
        }
    }

    if (seg == 0) {
        #pragma unroll
        for (int nf = 0; nf < 4; ++nf) {
            int c = (nW & 255) + nf * 16 + ln;
            float bb = bq[c];
            #pragma unroll
            for (int r = 0; r < 4; ++r) {
                int row = m0 + w * 16 + kg * 4 + r;
                Qb[(size_t)row * 256 + c] = f2bf(acc[nf][r] + bb);
            }
        }
    } else if (seg == 1) {
        #pragma unroll
        for (int nf = 0; nf < 4; ++nf) {
            int c = (nW & 255) + nf * 16 + ln;
            #pragma unroll
            for (int r = 0; r < 4; ++r) {
                int row = m0 + w * 16 + kg * 4 + r;
                Kb[(size_t)row * 256 + c] = f2bf(acc[nf][r]);
            }
        }
    } else if (seg == 2) {
        #pragma unroll
        for (int nf = 0; nf < 4; ++nf) {
            int c = (nW & 255) + nf * 16 + ln;
            int h = c >> 5, d = c & 31;
            float bb = bv[c];
            #pragma unroll
            for (int r = 0; r < 4; ++r) {
                int row = m0 + w * 16 + kg * 4 + r;
                int b = row >> 9, ml = row & 511;
                Vtb[((size_t)(b * 8 + h) * 32 + d) * 512 + ml] = f2bf(acc[nf][r] + bb);
            }
        }
    } else {
        // per-block max of P over the 64 rows -> private maxPart slot (no atomics)
        #pragma unroll
        for (int nf = 0; nf < 4; ++nf) {
            float mx = fmaxf(fmaxf(acc[nf][0], acc[nf][1]),
                             fmaxf(acc[nf][2], acc[nf][3]));
            mx = fmaxf(mx, __shfl_xor(mx, 16));
            mx = fmaxf(mx, __shfl_xor(mx, 32));
            if (l < 16) red[w][nf * 16 + ln] = mx;
        }
        __syncthreads();
        if (t < 64) {
            float m = fmaxf(fmaxf(red[0][t], red[1][t]),
                            fmaxf(red[2][t], red[3][t]));
            const int b = blockIdx.x >> 3;        // batch
            const int mblk = blockIdx.x & 7;      // 64-row block within batch
            maxPart[b * 2048 + mblk * 256 + (nW & 255) + t] = m;
        }
    }
}

// K2: MFMA flash attention. grid (32 q-tiles of 16, 8 h, 2 b) x 256 (4 waves).
// Wave w handles keys w*128..+127 (single-pass softmax). QK^T/PV via MFMA;
// K/Vt frags direct from global (L2). One cross-wave combine at end.
__global__ __launch_bounds__(256) void k_attn_mfma(
    const unsigned short* __restrict__ Qb,   // [1024][256] bf16
    const unsigned short* __restrict__ Kb,   // [1024][256] bf16
    const unsigned short* __restrict__ Vtb,  // [16][32][512] bf16
    const float* __restrict__ maxPart,       // [2][8][256]
    const float* __restrict__ br,
    unsigned short* __restrict__ attnb)      // [1024][256] bf16
{
    __shared__ __align__(16) unsigned short Plds[4][16][136];
    __shared__ float Olds[4][16][33];
    __shared__ float mlds[4][16], llds[4][16];
    __shared__ float scl[4][16], Li[16];
    __shared__ float qadd[32];

    const int t = threadIdx.x;
    const int w = t >> 6, l = t & 63;
    const int ln = l & 15, kg = l >> 4;
    const int q0 = blockIdx.x * 16;
    const int h = blockIdx.y, b = blockIdx.z;
    const int e0 = h * 32;
    const int bh = b * 8 + h;
    const float scale = 0.17677669529663687f;  // 1/sqrt(32)

    if (t < 32) {
        float m = maxPart[b * 2048 + e0 + t];
        #pragma unroll
        for (int j = 1; j < 8; ++j)
            m = fmaxf(m, maxPart[b * 2048 + j * 256 + e0 + t]);
        qadd[t] = m + br[e0 + t];
    }
    __syncthreads();

    // a-frag: Qr = (Qb + maxP + br) * scale, re-rounded to bf16
    bf16x8 af;
    {
        size_t qrow = (size_t)(b * NSEQ + q0 + ln) * 256 + e0 + kg * 8;
        bf16x8 qa = *(const bf16x8*)(Qb + qrow);
        #pragma unroll
        for (int j = 0; j < 8; ++j) {
            int d = kg * 8 + j;
            float qv = bf2f((unsigned short)qa[j]);
            af[j] = (short)f2bf((qv + qadd[d]) * scale);
        }
    }

    // QK^T: 8 key-frags of 16 (this wave's 128 keys)
    const int key0 = w * 128;
    f32x4 sc[8];
    #pragma unroll
    for (int kf = 0; kf < 8; ++kf) {
        size_t krow = (size_t)(b * NSEQ + key0 + kf * 16 + ln) * 256 + e0 + kg * 8;
        bf16x8 bfr = *(const bf16x8*)(Kb + krow);
        f32x4 z = {0.f, 0.f, 0.f, 0.f};
        sc[kf] = __builtin_amdgcn_mfma_f32_16x16x32_bf16(af, bfr, z, 0, 0, 0);
    }

    // single-pass softmax over this wave's 128 keys; lane owns q = kg*4+r
    float m_[4], l_[4];
    #pragma unroll
    for (int r = 0; r < 4; ++r) {
        float mx = sc[0][r];
        #pragma unroll
        for (int kf = 1; kf < 8; ++kf) mx = fmaxf(mx, sc[kf][r]);
        #pragma unroll
        for (int off = 1; off < 16; off <<= 1) mx = fmaxf(mx, __shfl_xor(mx, off));
        m_[r] = mx;
        float s = 0.f;
        #pragma unroll
        for (int kf = 0; kf < 8; ++kf) {
            float p = __expf(sc[kf][r] - mx);
            sc[kf][r] = p;
            s += p;
        }
        #pragma unroll
        for (int off = 1; off < 16; off <<= 1) s += __shfl_xor(s, off);
        l_[r] = s;
    }

    // P -> LDS (bf16), wave-private
    #pragma unroll
    for (int kf = 0; kf < 8; ++kf)
        #pragma unroll
        for (int r = 0; r < 4; ++r)
            Plds[w][kg * 4 + r][kf * 16 + ln] = f2bf(sc[kf][r]);

    // PV: O[16 q][32 d]
    f32x4 o[2] = {{0.f,0.f,0.f,0.f},{0.f,0.f,0.f,0.f}};
    #pragma unroll
    for (int ks = 0; ks < 4; ++ks) {
        bf16x8 pf = *(const bf16x8*)&Plds[w][ln][ks * 32 + kg * 8];
        #pragma unroll
        for (int df = 0; df < 2; ++df) {
            size_t vrow = ((size_t)bh * 32 + df * 16 + ln) * 512 + key0 + ks * 32 + kg * 8;
            bf16x8 vf = *(const bf16x8*)(Vtb + vrow);
            o[df] = __builtin_amdgcn_mfma_f32_16x16x32_bf16(pf, vf, o[df], 0, 0, 0);
        }
    }

    if (ln == 0) {
        #pragma unroll
        for (int r = 0; r < 4; ++r) {
            mlds[w][kg * 4 + r] = m_[r];
            llds[w][kg * 4 + r] = l_[r];
        }
    }
    #pragma unroll
    for (int df = 0; df < 2; ++df)
        #pragma unroll
        for (int r = 0; r < 4; ++r)
            Olds[w][kg * 4 + r][df * 16 + ln] = o[df][r];
    __syncthreads();

    if (t < 16) {
        float M = fmaxf(fmaxf(mlds[0][t], mlds[1][t]),
                        fmaxf(mlds[2][t], mlds[3][t]));
        float L = 0.f;
        #pragma unroll
        for (int wv = 0; wv < 4; ++wv) {
            float s = __expf(mlds[wv][t] - M);
            scl[wv][t] = s;
            L += s * llds[wv][t];
        }
        Li[t] = 1.f / L;
    }
    __syncthreads();

    #pragma unroll
    for (int i = 0; i < 2; ++i) {
        int idx = t + 256 * i;
        int q = idx >> 5, d = idx & 31;
        float acc = 0.f;
        #pragma unroll
        for (int wv = 0; wv < 4; ++wv)
            acc += scl[wv][q] * Olds[wv][q][d];
        attnb[(size_t)(b * NSEQ + q0 + q) * 256 + e0 + d] = f2bf(acc * Li[q]);
    }
}

// K3: out-projection, bf16 MFMA, split-K=4. grid (16 m, 4 n, 4 k) x 256.
__global__ __launch_bounds__(256) void k_ogemm_mfma(
    const unsigned short* __restrict__ Ab,   // attnb [1024][256] bf16
    const unsigned short* __restrict__ Wob,  // [256][256] bf16
    float* __restrict__ yPart)
{
    __shared__ __align__(16) unsigned short As_[64 * 72];
    __shared__ __align__(16) unsigned short Bs_[64 * 72];

    const int t = threadIdx.x;
    const int w = t >> 6, l = t & 63;
    const int ln = l & 15, kg = l >> 4;
    const int m0 = blockIdx.x * 64;
    const int n0 = blockIdx.y * 64;
    const int bz = blockIdx.z;

    const uint4* Ag = (const uint4*)Ab;   // [1024][32]
    const uint4* Wg = (const uint4*)Wob;  // [256][32]
    #pragma unroll
    for (int i = 0; i < 2; ++i) {
        int idx = i * 256 + t;            // 0..511
        int row = idx >> 3, c8 = idx & 7;
        *(uint4*)(As_ + row * 72 + c8 * 8) = Ag[(size_t)(m0 + row) * 32 + bz * 8 + c8];
        *(uint4*)(Bs_ + row * 72 + c8 * 8) = Wg[(size_t)(n0 + row) * 32 + bz * 8 + c8];
    }
    __syncthreads();

    f32x4 acc[4] = {{0.f,0.f,0.f,0.f},{0.f,0.f,0.f,0.f},
                    {0.f,0.f,0.f,0.f},{0.f,0.f,0.f,0.f}};
    const int arow = (w << 4) + ln;
    #pragma unroll
    for (int ks = 0; ks < 2; ++ks) {
        bf16x8 a = *(const bf16x8*)(As_ + arow * 72 + ks * 32 + kg * 8);
        #pragma unroll
        for (int nf = 0; nf < 4; ++nf) {
            bf16x8 b = *(const bf16x8*)(Bs_ + (nf * 16 + ln) * 72 + ks * 32 + kg * 8);
            acc[nf] = __builtin_amdgcn_mfma_f32_16x16x32_bf16(a, b, acc[nf], 0, 0, 0);
        }
    }

    float* dst = yPart + (size_t)bz * (1024 * 256);
    #pragma unroll
    for (int nf = 0; nf < 4; ++nf) {
        #pragma unroll
        for (int r = 0; r < 4; ++r) {
            int row = m0 + w * 16 + kg * 4 + r;
            dst[(size_t)row * 256 + n0 + nf * 16 + ln] = acc[nf][r];
        }
    }
}

// K4: y = x + bo + sum(yPart) ; LN1 ; LN2. grid 256 x 256; 4 rows/block.
__global__ __launch_bounds__(256) void k_lnorm(
    const float* __restrict__ yP, const float* __restrict__ x,
    const float* __restrict__ bo,
    const float* __restrict__ g1, const float* __restrict__ b1,
    const float* __restrict__ g2, const float* __restrict__ b2,
    float* __restrict__ out)
{
    __shared__ float red[4][4][2];
    const int t = threadIdx.x;
    const int r0 = blockIdx.x * 4;
    const int c = t;
    const int wid = t >> 6, lane = t & 63;

    float y[4];
    #pragma unroll
    for (int r = 0; r < 4; ++r) {
        size_t off = (size_t)(r0 + r) * 256 + c;
        y[r] = x[off] + bo[c] + yP[off] + yP[262144 + off]
             + yP[524288 + off] + yP[786432 + off];
    }

    // LN1
    #pragma unroll
    for (int r = 0; r < 4; ++r) {
        float s = y[r], s2 = y[r] * y[r];
        #pragma unroll
        for (int off = 32; off > 0; off >>= 1) {
            s  += __shfl_xor(s, off);
            s2 += __shfl_xor(s2, off);
        }
        if (lane == 0) { red[wid][r][0] = s; red[wid][r][1] = s2; }
    }
    __syncthreads();
    float t1[4];
    #pragma unroll
    for (int r = 0; r < 4; ++r) {
        float s  = red[0][r][0] + red[1][r][0] + red[2][r][0] + red[3][r][0];
        float s2 = red[0][r][1] + red[1][r][1] + red[2][r][1] + red[3][r][1];
        float mu = s * (1.f / 256.f);
        float var = s2 * (1.f / 256.f) - mu * mu;
        float rs = rsqrtf(var + 1e-5f);
        t1[r] = (y[r] - mu) * rs * g1[c] + b1[c];
    }
    __syncthreads();

    // LN2
    #pragma unroll
    for (int r = 0; r < 4; ++r) {
        float s = t1[r], s2 = t1[r] * t1[r];
        #pragma unroll
        for (int off = 32; off > 0; off >>= 1) {
            s  += __shfl_xor(s, off);
            s2 += __shfl_xor(s2, off);
        }
        if (lane == 0) { red[wid][r][0] = s; red[wid][r][1] = s2; }
    }
    __syncthreads();
    #pragma unroll
    for (int r = 0; r < 4; ++r) {
        float s  = red[0][r][0] + red[1][r][0] + red[2][r][0] + red[3][r][0];
        float s2 = red[0][r][1] + red[1][r][1] + red[2][r][1] + red[3][r][1];
        float mu = s * (1.f / 256.f);
        float var = s2 * (1.f / 256.f) - mu * mu;
        float rs = rsqrtf(var + 1e-5f);
        out[(size_t)(r0 + r) * 256 + c] = (t1[r] - mu) * rs * g2[c] + b2[c];
    }
}

extern "C" void kernel_launch(void* const* d_in, const int* in_sizes, int n_in,
                              void* d_out, int out_size, void* d_ws, size_t ws_size,
                              hipStream_t stream)
{
    const float* x  = (const float*)d_in[0];
    const float* Wq = (const float*)d_in[1];
    const float* bq = (const float*)d_in[2];
    const float* Wk = (const float*)d_in[3];
    const float* bk = (const float*)d_in[4];   // cancels in softmax (unused)
    const float* Wv = (const float*)d_in[5];
    const float* bv = (const float*)d_in[6];
    const float* Wr = (const float*)d_in[7];
    const float* br = (const float*)d_in[8];
    const float* Wo = (const float*)d_in[9];
    const float* bo = (const float*)d_in[10];
    const float* g1 = (const float*)d_in[11];
    const float* b1 = (const float*)d_in[12];
    const float* g2 = (const float*)d_in[13];
    const float* b2 = (const float*)d_in[14];
    float* out = (float*)d_out;
    (void)bk;

    unsigned short* u = (unsigned short*)d_ws;
    unsigned short* Qb    = u;               // 1024*256
    unsigned short* Kb    = u + 262144;      // 1024*256
    unsigned short* Vtb   = u + 524288;      // 16*32*512
    unsigned short* attnb = u + 786432;      // 1024*256
    unsigned short* Wob   = u + 1048576;     // 256*256
    float* maxPart = (float*)(u + 1114112);  // [2][8][256] (byte 2228224)
    float* yP      = (float*)(u + 1122304);  // 4*1024*256 fp32 (byte 2244608)

    k_gemm_mfma<<<dim3(16, 17), 256, 0, stream>>>(x, Wq, Wk, Wv, Wr, Wo, bq, bv,
                                                  Qb, Kb, Vtb, Wob, maxPart);
    k_attn_mfma<<<dim3(32, 8, 2), 256, 0, stream>>>(Qb, Kb, Vtb, maxPart, br, attnb);
    k_ogemm_mfma<<<dim3(16, 4, 4), 256, 0, stream>>>(attnb, Wob, yP);
    k_lnorm<<<256, 256, 0, stream>>>(yP, x, bo, g1, b1, g2, b2, out);
}